// Round 1
// 617.126 us; speedup vs baseline: 1.1231x; 1.1231x over previous
//
#include <hip/hip_runtime.h>

// Problem constants
#define N_LIC 40000
#define N_EMP 80000
#define N_CON 60000
#define D_EMP 128
#define D_CON 192
#define HDIM  256
#define E_P   1280000
#define E_Q   640000

#define NR 8                 // dst ranges == XCD count
#define RNG (N_LIC / NR)     // 5000 dst nodes per range

// -------------------- workspace layout (4-byte units) --------------------
#define OFF_AGGP   0                                   // 40000x128 bf16 -> 2,560,000 dw
#define OFF_AGGQ   (OFF_AGGP + 2560000)                // 40000x192 bf16 -> 3,840,000 dw
#define OFF_XL     (OFF_AGGQ + 3840000)                // 40000x256 bf16 -> 5,120,000 dw
#define OFF_BPK    (OFF_XL + 5120000)                  // 256x576 bf16 -> 73,728 dw
#define OFF_BIAS   (OFF_BPK + 73728)                   // 256 f
#define OFF_CNT    (OFF_BIAS + 256)                    // 80000 i (P then Q)
#define OFF_OFFP   (OFF_CNT + 2 * N_LIC)               // 40001 i
#define OFF_OFFQ   (OFF_OFFP + N_LIC + 1)              // 40001 i
#define OFF_CURP   (OFF_OFFQ + N_LIC + 1)              // 40000 i
#define OFF_CURQ   (OFF_CURP + N_LIC)                  // 40000 i
#define OFF_SRTP   (OFF_CURQ + N_LIC)                  // 1,280,000 i
#define OFF_SRTQ   (OFF_SRTP + E_P)                    // 640,000 i
// total ~13.75M dw = 55 MB

typedef short bf16x8 __attribute__((ext_vector_type(8)));
typedef float f32x4 __attribute__((ext_vector_type(4)));

__device__ __forceinline__ ushort f2bf(float f) {
    union { float f; uint u; } v; v.f = f;
    return (ushort)((v.u + 0x7fffu + ((v.u >> 16) & 1u)) >> 16);
}

// -------------------- prep: pack B = [Wl_p; Wl_q; Wr_p+Wr_q] transposed to [n][k] bf16 ----
__global__ void prep_kernel(const float* __restrict__ Wlp, const float* __restrict__ Wlq,
                            const float* __restrict__ Wrp, const float* __restrict__ Wrq,
                            const float* __restrict__ bp, const float* __restrict__ bq,
                            ushort* __restrict__ Bpk, float* __restrict__ bias) {
    int tid = blockIdx.x * 256 + threadIdx.x;
    if (tid < 256 * 576) {
        int n = tid / 576, k = tid - n * 576;
        float v;
        if (k < 128)      v = Wlp[k * 256 + n];
        else if (k < 320) v = Wlq[(k - 128) * 256 + n];
        else              v = Wrp[(k - 320) * 256 + n] + Wrq[(k - 320) * 256 + n];
        Bpk[tid] = f2bf(v);
    } else if (tid < 256 * 576 + 256) {
        int j = tid - 256 * 576;
        bias[j] = bp[j] + bq[j];
    }
}

// -------------------- convert x_lic to bf16 (1 float4 per thread) --------------------
__global__ void convert_kernel(const float* __restrict__ x, ushort* __restrict__ y) {
    int tid = blockIdx.x * 256 + threadIdx.x;
    float4 v = ((const float4*)x)[tid];
    uint2 o;
    o.x = (uint)f2bf(v.x) | ((uint)f2bf(v.y) << 16);
    o.y = (uint)f2bf(v.z) | ((uint)f2bf(v.w) << 16);
    ((uint2*)y)[tid] = o;
}

// -------------------- histogram, dst-range partitioned with XCD affinity --------------------
// blockIdx.x = chunk*NR + r ; round-robin dispatch puts all blocks of range r on one XCD,
// so each cnt[] line is only ever touched by a single XCD's L2 (no cross-XCD atomic bounce).
__global__ void count_kernel(const int* __restrict__ dp, const int* __restrict__ dq,
                             int* __restrict__ cnt) {
    int r = blockIdx.x & (NR - 1);
    int chunk = blockIdx.x >> 3;
    int lo = r * RNG, hi = lo + RNG;
    int tid = chunk * 256 + threadIdx.x;
    if (tid < E_P) {
        int d = dp[tid];
        if (d >= lo && d < hi) atomicAdd(&cnt[d], 1);
    } else if (tid < E_P + E_Q) {
        int d = dq[tid - E_P];
        if (d >= lo && d < hi) atomicAdd(&cnt[N_LIC + d], 1);
    }
}

// -------------------- single-block exclusive scan + cursor init (one block/relation) ----
__global__ __launch_bounds__(1024) void scan_kernel(const int* __restrict__ cnt_all,
                                                    int* __restrict__ offp, int* __restrict__ offq,
                                                    int* __restrict__ curp, int* __restrict__ curq) {
    const int rel = blockIdx.x;
    const int* cnt = cnt_all + rel * N_LIC;
    int* offs = rel == 0 ? offp : offq;
    int* cur  = rel == 0 ? curp : curq;
    const int CH = 40;
    int t = threadIdx.x;
    int base = t * CH;
    int s = 0;
    #pragma unroll 4
    for (int i = 0; i < CH; i++) {
        int idx = base + i;
        if (idx < N_LIC) s += cnt[idx];
    }
    __shared__ int part[1024];
    part[t] = s;
    __syncthreads();
    for (int off = 1; off < 1024; off <<= 1) {
        int v = (t >= off) ? part[t - off] : 0;
        __syncthreads();
        part[t] += v;
        __syncthreads();
    }
    int run = (t > 0) ? part[t - 1] : 0;
    for (int i = 0; i < CH; i++) {
        int idx = base + i;
        if (idx < N_LIC) {
            offs[idx] = run;
            cur[idx] = run;
            run += cnt[idx];
        }
    }
    if (t == 0) offs[N_LIC] = part[1023];
}

// -------------------- bucket-fill, dst-range partitioned with XCD affinity --------------------
// Each srt[] cache line belongs to one dst bucket -> one range -> one XCD. Lines accumulate
// all 16 stores in that XCD's L2 and write back once (kills the 16x write amplification).
__global__ void fill_kernel(const int* __restrict__ sp, const int* __restrict__ dp,
                            const int* __restrict__ sq, const int* __restrict__ dq,
                            int* __restrict__ curp, int* __restrict__ curq,
                            int* __restrict__ srtp, int* __restrict__ srtq) {
    int r = blockIdx.x & (NR - 1);
    int chunk = blockIdx.x >> 3;
    int lo = r * RNG, hi = lo + RNG;
    int tid = chunk * 256 + threadIdx.x;
    if (tid < E_P) {
        int d = dp[tid];
        if (d >= lo && d < hi) {
            int pos = atomicAdd(&curp[d], 1);
            srtp[pos] = sp[tid];
        }
    } else if (tid < E_P + E_Q) {
        int e = tid - E_P;
        int d = dq[e];
        if (d >= lo && d < hi) {
            int pos = atomicAdd(&curq[d], 1);
            srtq[pos] = sq[e];
        }
    }
}

// -------------------- aggregate P: 32 lanes/node, D=128, fp32 in -> bf16 out ------------
__global__ __launch_bounds__(256) void aggP_kernel(const float* __restrict__ x,
                                                   const int* __restrict__ offs,
                                                   const int* __restrict__ sorted,
                                                   ushort* __restrict__ agg) {
    int g = blockIdx.x * 8 + (threadIdx.x >> 5);
    int c = threadIdx.x & 31;
    int beg = offs[g], end = offs[g + 1];
    float4 acc = {0.f, 0.f, 0.f, 0.f};
    for (int eb = beg; eb < end; eb += 32) {
        int n = end - eb; if (n > 32) n = 32;
        int my = (c < n) ? sorted[eb + c] : 0;
        for (int j = 0; j < n; j++) {
            int s = __shfl(my, j, 32);
            float4 v = *(const float4*)(x + (size_t)s * D_EMP + c * 4);
            acc.x += v.x; acc.y += v.y; acc.z += v.z; acc.w += v.w;
        }
    }
    float inv = 1.0f / fmaxf((float)(end - beg), 1.0f);
    uint2 o;
    o.x = (uint)f2bf(acc.x * inv) | ((uint)f2bf(acc.y * inv) << 16);
    o.y = (uint)f2bf(acc.z * inv) | ((uint)f2bf(acc.w * inv) << 16);
    *(uint2*)(agg + (size_t)g * D_EMP + c * 4) = o;
}

// -------------------- aggregate Q: 16 lanes/node, D=192, fp32 in -> bf16 out ------------
__global__ __launch_bounds__(256) void aggQ_kernel(const float* __restrict__ x,
                                                   const int* __restrict__ offs,
                                                   const int* __restrict__ sorted,
                                                   ushort* __restrict__ agg) {
    int g = blockIdx.x * 16 + (threadIdx.x >> 4);
    int c = threadIdx.x & 15;
    int beg = offs[g], end = offs[g + 1];
    float4 a0 = {0,0,0,0}, a1 = {0,0,0,0}, a2 = {0,0,0,0};
    for (int eb = beg; eb < end; eb += 16) {
        int n = end - eb; if (n > 16) n = 16;
        int my = (c < n) ? sorted[eb + c] : 0;
        for (int j = 0; j < n; j++) {
            int s = __shfl(my, j, 16);
            const float* row = x + (size_t)s * D_CON + c * 12;
            float4 v0 = *(const float4*)(row + 0);
            float4 v1 = *(const float4*)(row + 4);
            float4 v2 = *(const float4*)(row + 8);
            a0.x += v0.x; a0.y += v0.y; a0.z += v0.z; a0.w += v0.w;
            a1.x += v1.x; a1.y += v1.y; a1.z += v1.z; a1.w += v1.w;
            a2.x += v2.x; a2.y += v2.y; a2.z += v2.z; a2.w += v2.w;
        }
    }
    float inv = 1.0f / fmaxf((float)(end - beg), 1.0f);
    ushort* o = agg + (size_t)g * D_CON + c * 12;
    uint2 w0, w1, w2;
    w0.x = (uint)f2bf(a0.x*inv) | ((uint)f2bf(a0.y*inv) << 16);
    w0.y = (uint)f2bf(a0.z*inv) | ((uint)f2bf(a0.w*inv) << 16);
    w1.x = (uint)f2bf(a1.x*inv) | ((uint)f2bf(a1.y*inv) << 16);
    w1.y = (uint)f2bf(a1.z*inv) | ((uint)f2bf(a1.w*inv) << 16);
    w2.x = (uint)f2bf(a2.x*inv) | ((uint)f2bf(a2.y*inv) << 16);
    w2.y = (uint)f2bf(a2.z*inv) | ((uint)f2bf(a2.w*inv) << 16);
    *(uint2*)(o + 0) = w0;
    *(uint2*)(o + 4) = w1;
    *(uint2*)(o + 8) = w2;
}

// -------------------- MFMA bf16 GEMM + bias + relu --------------------
// C[40000,256] = relu(0.5*([aggp|aggq|xl] @ B + bias)); B prepacked [n=256][k=576] bf16.
// BM=64, BN=256 (full), BK=32, 4 waves, each wave 64 rows x 64 cols = 4x4 mfma tiles.
__global__ __launch_bounds__(256) void gemm_kernel(
    const ushort* __restrict__ aggp, const ushort* __restrict__ aggq,
    const ushort* __restrict__ xl, const ushort* __restrict__ Bpk,
    const float* __restrict__ bias, float* __restrict__ out)
{
    __shared__ __align__(16) ushort As[64 * 40];   // [m][k], k padded 32->40
    __shared__ __align__(16) ushort Bs[256 * 40];  // [n][k]

    const int t = threadIdx.x;
    const int m0 = blockIdx.x * 64;
    const int lane = t & 63;
    const int wave = t >> 6;
    const int arow = t >> 2;   // 0..63
    const int achk = t & 3;    // 0..3
    const int l15 = lane & 15;
    const int lh  = lane >> 4; // 0..3

    f32x4 acc[4][4];
    #pragma unroll
    for (int i = 0; i < 4; i++)
        #pragma unroll
        for (int j = 0; j < 4; j++)
            acc[i][j] = (f32x4){0.f, 0.f, 0.f, 0.f};

    for (int k0 = 0; k0 < 576; k0 += 32) {
        const ushort* Asrc; int ldA; int ko;
        if (k0 < 128)      { Asrc = aggp; ldA = 128; ko = k0; }
        else if (k0 < 320) { Asrc = aggq; ldA = 192; ko = k0 - 128; }
        else               { Asrc = xl;   ldA = 256; ko = k0 - 320; }

        // stage A tile: 64 rows x 32 k (16B per thread)
        {
            const uint4 v = *(const uint4*)(Asrc + (size_t)(m0 + arow) * ldA + ko + achk * 8);
            *(uint4*)(As + arow * 40 + achk * 8) = v;
        }
        // stage B tile: 256 cols x 32 k (4 x 16B per thread)
        #pragma unroll
        for (int i = 0; i < 4; i++) {
            int col = arow + i * 64;
            const uint4 v = *(const uint4*)(Bpk + (size_t)col * 576 + k0 + achk * 8);
            *(uint4*)(Bs + col * 40 + achk * 8) = v;
        }
        __syncthreads();

        bf16x8 af[4], bfr[4];
        #pragma unroll
        for (int mt = 0; mt < 4; mt++)
            af[mt] = *(const bf16x8*)(As + (mt * 16 + l15) * 40 + lh * 8);
        #pragma unroll
        for (int nt = 0; nt < 4; nt++)
            bfr[nt] = *(const bf16x8*)(Bs + (wave * 64 + nt * 16 + l15) * 40 + lh * 8);

        #pragma unroll
        for (int mt = 0; mt < 4; mt++)
            #pragma unroll
            for (int nt = 0; nt < 4; nt++)
                acc[mt][nt] = __builtin_amdgcn_mfma_f32_16x16x32_bf16(af[mt], bfr[nt], acc[mt][nt], 0, 0, 0);

        __syncthreads();
    }

    // epilogue: C/D layout col=lane&15, row=(lane>>4)*4+reg
    #pragma unroll
    for (int nt = 0; nt < 4; nt++) {
        int n = wave * 64 + nt * 16 + l15;
        float bv = bias[n];
        #pragma unroll
        for (int mt = 0; mt < 4; mt++) {
            #pragma unroll
            for (int r = 0; r < 4; r++) {
                int m = m0 + mt * 16 + lh * 4 + r;
                float v = 0.5f * (acc[mt][nt][r] + bv);
                out[(size_t)m * 256 + n] = fmaxf(v, 0.f);
            }
        }
    }
}

// -------------------- launch --------------------
extern "C" void kernel_launch(void* const* d_in, const int* in_sizes, int n_in,
                              void* d_out, int out_size, void* d_ws, size_t ws_size,
                              hipStream_t stream) {
    const float* x_lic = (const float*)d_in[0];
    const float* x_emp = (const float*)d_in[1];
    const float* x_con = (const float*)d_in[2];
    const float* Wl_p  = (const float*)d_in[3];
    const float* Wr_p  = (const float*)d_in[4];
    const float* b_p   = (const float*)d_in[5];
    const float* Wl_q  = (const float*)d_in[6];
    const float* Wr_q  = (const float*)d_in[7];
    const float* b_q   = (const float*)d_in[8];
    const int* ei_p_src = (const int*)d_in[9];
    const int* ei_p_dst = (const int*)d_in[10];
    const int* ei_q_src = (const int*)d_in[11];
    const int* ei_q_dst = (const int*)d_in[12];

    float* ws = (float*)d_ws;
    ushort* aggp = (ushort*)(ws + OFF_AGGP);
    ushort* aggq = (ushort*)(ws + OFF_AGGQ);
    ushort* xl   = (ushort*)(ws + OFF_XL);
    ushort* Bpk  = (ushort*)(ws + OFF_BPK);
    float* bias  = ws + OFF_BIAS;
    int* cnt  = (int*)(ws + OFF_CNT);
    int* offp = (int*)(ws + OFF_OFFP);
    int* offq = (int*)(ws + OFF_OFFQ);
    int* curp = (int*)(ws + OFF_CURP);
    int* curq = (int*)(ws + OFF_CURQ);
    int* srtp = (int*)(ws + OFF_SRTP);
    int* srtq = (int*)(ws + OFF_SRTQ);
    float* out = (float*)d_out;

    hipMemsetAsync(cnt, 0, 2 * N_LIC * sizeof(int), stream);

    prep_kernel<<<(256 * 576 + 256 + 255) / 256, 256, 0, stream>>>(Wl_p, Wl_q, Wr_p, Wr_q, b_p, b_q, Bpk, bias);

    convert_kernel<<<(N_LIC * 256 / 4) / 256, 256, 0, stream>>>(x_lic, xl);

    const int NCHUNK = (E_P + E_Q + 255) / 256;  // 7500 edge chunks
    count_kernel<<<NCHUNK * NR, 256, 0, stream>>>(ei_p_dst, ei_q_dst, cnt);

    scan_kernel<<<2, 1024, 0, stream>>>(cnt, offp, offq, curp, curq);

    fill_kernel<<<NCHUNK * NR, 256, 0, stream>>>(ei_p_src, ei_p_dst, ei_q_src, ei_q_dst,
                                                 curp, curq, srtp, srtq);

    aggP_kernel<<<N_LIC / 8, 256, 0, stream>>>(x_emp, offp, srtp, aggp);
    aggQ_kernel<<<N_LIC / 16, 256, 0, stream>>>(x_con, offq, srtq, aggq);

    gemm_kernel<<<N_LIC / 64, 256, 0, stream>>>(aggp, aggq, xl, Bpk, bias, out);
}

// Round 2
// 528.319 us; speedup vs baseline: 1.3119x; 1.1681x over previous
//
#include <hip/hip_runtime.h>

// Problem constants
#define N_LIC 40000
#define N_EMP 80000
#define N_CON 60000
#define D_EMP 128
#define D_CON 192
#define HDIM  256
#define E_P   1280000
#define E_Q   640000

#define NR 8                 // dst ranges == XCD count
#define RNG (N_LIC / NR)     // 5000 dst nodes per range

// -------------------- workspace layout (4-byte units) --------------------
#define OFF_AGGP   0                                   // 40000x128 bf16 -> 2,560,000 dw
#define OFF_AGGQ   (OFF_AGGP + 2560000)                // 40000x192 bf16 -> 3,840,000 dw
#define OFF_XL     (OFF_AGGQ + 3840000)                // 40000x256 bf16 -> 5,120,000 dw
#define OFF_BPK    (OFF_XL + 5120000)                  // 256x576 bf16 -> 73,728 dw
#define OFF_BIAS   (OFF_BPK + 73728)                   // 256 f
#define OFF_CNT    (OFF_BIAS + 256)                    // 80000 i (P then Q)
#define OFF_CURS   (OFF_CNT + 2 * N_LIC)               // 128 i (2 cursors, line-padded)
#define OFF_OFFP   (OFF_CURS + 128)                    // 40000 i
#define OFF_OFFQ   (OFF_OFFP + N_LIC)                  // 40000 i
#define OFF_CURP   (OFF_OFFQ + N_LIC)                  // 40000 i
#define OFF_CURQ   (OFF_CURP + N_LIC)                  // 40000 i
#define OFF_SRTP   (OFF_CURQ + N_LIC)                  // 1,280,000 i
#define OFF_SRTQ   (OFF_SRTP + E_P)                    // 640,000 i
// total ~13.75M dw = 55 MB

typedef short bf16x8 __attribute__((ext_vector_type(8)));
typedef float f32x4 __attribute__((ext_vector_type(4)));

__device__ __forceinline__ ushort f2bf(float f) {
    union { float f; uint u; } v; v.f = f;
    return (ushort)((v.u + 0x7fffu + ((v.u >> 16) & 1u)) >> 16);
}

// -------------------- prep: pack B = [Wl_p; Wl_q; Wr_p+Wr_q] transposed to [n][k] bf16 ----
__global__ void prep_kernel(const float* __restrict__ Wlp, const float* __restrict__ Wlq,
                            const float* __restrict__ Wrp, const float* __restrict__ Wrq,
                            const float* __restrict__ bp, const float* __restrict__ bq,
                            ushort* __restrict__ Bpk, float* __restrict__ bias) {
    int tid = blockIdx.x * 256 + threadIdx.x;
    if (tid < 256 * 576) {
        int n = tid / 576, k = tid - n * 576;
        float v;
        if (k < 128)      v = Wlp[k * 256 + n];
        else if (k < 320) v = Wlq[(k - 128) * 256 + n];
        else              v = Wrp[(k - 320) * 256 + n] + Wrq[(k - 320) * 256 + n];
        Bpk[tid] = f2bf(v);
    } else if (tid < 256 * 576 + 256) {
        int j = tid - 256 * 576;
        bias[j] = bp[j] + bq[j];
    }
}

// -------------------- convert x_lic to bf16 (1 float4 per thread) --------------------
__global__ void convert_kernel(const float* __restrict__ x, ushort* __restrict__ y) {
    int tid = blockIdx.x * 256 + threadIdx.x;
    float4 v = ((const float4*)x)[tid];
    uint2 o;
    o.x = (uint)f2bf(v.x) | ((uint)f2bf(v.y) << 16);
    o.y = (uint)f2bf(v.z) | ((uint)f2bf(v.w) << 16);
    ((uint2*)y)[tid] = o;
}

// -------------------- histogram, dst-range partitioned with XCD affinity --------------------
// blockIdx.x = chunk*NR + r ; round-robin dispatch puts all blocks of range r on one XCD,
// so each cnt[] line is only ever touched by a single XCD's L2 (no cross-XCD atomic bounce).
__global__ void count_kernel(const int* __restrict__ dp, const int* __restrict__ dq,
                             int* __restrict__ cnt) {
    int r = blockIdx.x & (NR - 1);
    int chunk = blockIdx.x >> 3;
    int lo = r * RNG, hi = lo + RNG;
    int tid = chunk * 256 + threadIdx.x;
    if (tid < E_P) {
        int d = dp[tid];
        if (d >= lo && d < hi) atomicAdd(&cnt[d], 1);
    } else if (tid < E_P + E_Q) {
        int d = dq[tid - E_P];
        if (d >= lo && d < hi) atomicAdd(&cnt[N_LIC + d], 1);
    }
}

// -------------------- bucket-start assignment via atomic bump allocator --------------------
// Bucket ORDER is irrelevant (agg uses beg + cnt, fill uses cur only), so no ordered prefix
// scan is needed. Each 64-lane wave scans its counts (shfl_up), the leader claims a span
// with one atomicAdd, lanes write offs/cur. 1250 waves, fully parallel, coalesced.
__global__ __launch_bounds__(256) void assign_kernel(const int* __restrict__ cnt,
                                                     int* __restrict__ offp, int* __restrict__ offq,
                                                     int* __restrict__ curp, int* __restrict__ curq,
                                                     int* __restrict__ cursors) {
    int tid = blockIdx.x * 256 + threadIdx.x;
    int lane = threadIdx.x & 63;
    bool valid = tid < 2 * N_LIC;
    int c = valid ? cnt[tid] : 0;
    int inc = c;
    #pragma unroll
    for (int off = 1; off < 64; off <<= 1) {
        int v = __shfl_up(inc, off, 64);
        if (lane >= off) inc += v;
    }
    int excl = inc - c;
    int wtot = __shfl(inc, 63, 64);
    int rel = (tid >= N_LIC) ? 1 : 0;   // wave-uniform: N_LIC % 64 == 0
    int base = 0;
    if (lane == 0 && wtot > 0) base = atomicAdd(&cursors[rel * 32], wtot);
    base = __shfl(base, 0, 64);
    if (valid) {
        int start = base + excl;
        if (rel == 0) { offp[tid] = start; curp[tid] = start; }
        else          { offq[tid - N_LIC] = start; curq[tid - N_LIC] = start; }
    }
}

// -------------------- bucket-fill, dst-range partitioned with XCD affinity --------------------
// Each srt[] cache line belongs to one dst bucket -> one range -> one XCD. Lines accumulate
// all 16 stores in that XCD's L2 and write back once (kills the 16x write amplification).
__global__ void fill_kernel(const int* __restrict__ sp, const int* __restrict__ dp,
                            const int* __restrict__ sq, const int* __restrict__ dq,
                            int* __restrict__ curp, int* __restrict__ curq,
                            int* __restrict__ srtp, int* __restrict__ srtq) {
    int r = blockIdx.x & (NR - 1);
    int chunk = blockIdx.x >> 3;
    int lo = r * RNG, hi = lo + RNG;
    int tid = chunk * 256 + threadIdx.x;
    if (tid < E_P) {
        int d = dp[tid];
        if (d >= lo && d < hi) {
            int pos = atomicAdd(&curp[d], 1);
            srtp[pos] = sp[tid];
        }
    } else if (tid < E_P + E_Q) {
        int e = tid - E_P;
        int d = dq[e];
        if (d >= lo && d < hi) {
            int pos = atomicAdd(&curq[d], 1);
            srtq[pos] = sq[e];
        }
    }
}

// -------------------- aggregate P: 32 lanes/node, D=128, fp32 in -> bf16 out ------------
__global__ __launch_bounds__(256) void aggP_kernel(const float* __restrict__ x,
                                                   const int* __restrict__ offs,
                                                   const int* __restrict__ cnt,
                                                   const int* __restrict__ sorted,
                                                   ushort* __restrict__ agg) {
    int g = blockIdx.x * 8 + (threadIdx.x >> 5);
    int c = threadIdx.x & 31;
    int beg = offs[g], deg = cnt[g], end = beg + deg;
    float4 acc = {0.f, 0.f, 0.f, 0.f};
    for (int eb = beg; eb < end; eb += 32) {
        int n = end - eb; if (n > 32) n = 32;
        int my = (c < n) ? sorted[eb + c] : 0;
        for (int j = 0; j < n; j++) {
            int s = __shfl(my, j, 32);
            float4 v = *(const float4*)(x + (size_t)s * D_EMP + c * 4);
            acc.x += v.x; acc.y += v.y; acc.z += v.z; acc.w += v.w;
        }
    }
    float inv = 1.0f / fmaxf((float)deg, 1.0f);
    uint2 o;
    o.x = (uint)f2bf(acc.x * inv) | ((uint)f2bf(acc.y * inv) << 16);
    o.y = (uint)f2bf(acc.z * inv) | ((uint)f2bf(acc.w * inv) << 16);
    *(uint2*)(agg + (size_t)g * D_EMP + c * 4) = o;
}

// -------------------- aggregate Q: 16 lanes/node, D=192, fp32 in -> bf16 out ------------
__global__ __launch_bounds__(256) void aggQ_kernel(const float* __restrict__ x,
                                                   const int* __restrict__ offs,
                                                   const int* __restrict__ cnt,
                                                   const int* __restrict__ sorted,
                                                   ushort* __restrict__ agg) {
    int g = blockIdx.x * 16 + (threadIdx.x >> 4);
    int c = threadIdx.x & 15;
    int beg = offs[g], deg = cnt[g], end = beg + deg;
    float4 a0 = {0,0,0,0}, a1 = {0,0,0,0}, a2 = {0,0,0,0};
    for (int eb = beg; eb < end; eb += 16) {
        int n = end - eb; if (n > 16) n = 16;
        int my = (c < n) ? sorted[eb + c] : 0;
        for (int j = 0; j < n; j++) {
            int s = __shfl(my, j, 16);
            const float* row = x + (size_t)s * D_CON + c * 12;
            float4 v0 = *(const float4*)(row + 0);
            float4 v1 = *(const float4*)(row + 4);
            float4 v2 = *(const float4*)(row + 8);
            a0.x += v0.x; a0.y += v0.y; a0.z += v0.z; a0.w += v0.w;
            a1.x += v1.x; a1.y += v1.y; a1.z += v1.z; a1.w += v1.w;
            a2.x += v2.x; a2.y += v2.y; a2.z += v2.z; a2.w += v2.w;
        }
    }
    float inv = 1.0f / fmaxf((float)deg, 1.0f);
    ushort* o = agg + (size_t)g * D_CON + c * 12;
    uint2 w0, w1, w2;
    w0.x = (uint)f2bf(a0.x*inv) | ((uint)f2bf(a0.y*inv) << 16);
    w0.y = (uint)f2bf(a0.z*inv) | ((uint)f2bf(a0.w*inv) << 16);
    w1.x = (uint)f2bf(a1.x*inv) | ((uint)f2bf(a1.y*inv) << 16);
    w1.y = (uint)f2bf(a1.z*inv) | ((uint)f2bf(a1.w*inv) << 16);
    w2.x = (uint)f2bf(a2.x*inv) | ((uint)f2bf(a2.y*inv) << 16);
    w2.y = (uint)f2bf(a2.z*inv) | ((uint)f2bf(a2.w*inv) << 16);
    *(uint2*)(o + 0) = w0;
    *(uint2*)(o + 4) = w1;
    *(uint2*)(o + 8) = w2;
}

// -------------------- MFMA bf16 GEMM + bias + relu --------------------
// C[40000,256] = relu(0.5*([aggp|aggq|xl] @ B + bias)); B prepacked [n=256][k=576] bf16.
// BM=64, BN=256 (full), BK=32, 4 waves, each wave 64 rows x 64 cols = 4x4 mfma tiles.
__global__ __launch_bounds__(256) void gemm_kernel(
    const ushort* __restrict__ aggp, const ushort* __restrict__ aggq,
    const ushort* __restrict__ xl, const ushort* __restrict__ Bpk,
    const float* __restrict__ bias, float* __restrict__ out)
{
    __shared__ __align__(16) ushort As[64 * 40];   // [m][k], k padded 32->40
    __shared__ __align__(16) ushort Bs[256 * 40];  // [n][k]

    const int t = threadIdx.x;
    const int m0 = blockIdx.x * 64;
    const int lane = t & 63;
    const int wave = t >> 6;
    const int arow = t >> 2;   // 0..63
    const int achk = t & 3;    // 0..3
    const int l15 = lane & 15;
    const int lh  = lane >> 4; // 0..3

    f32x4 acc[4][4];
    #pragma unroll
    for (int i = 0; i < 4; i++)
        #pragma unroll
        for (int j = 0; j < 4; j++)
            acc[i][j] = (f32x4){0.f, 0.f, 0.f, 0.f};

    for (int k0 = 0; k0 < 576; k0 += 32) {
        const ushort* Asrc; int ldA; int ko;
        if (k0 < 128)      { Asrc = aggp; ldA = 128; ko = k0; }
        else if (k0 < 320) { Asrc = aggq; ldA = 192; ko = k0 - 128; }
        else               { Asrc = xl;   ldA = 256; ko = k0 - 320; }

        // stage A tile: 64 rows x 32 k (16B per thread)
        {
            const uint4 v = *(const uint4*)(Asrc + (size_t)(m0 + arow) * ldA + ko + achk * 8);
            *(uint4*)(As + arow * 40 + achk * 8) = v;
        }
        // stage B tile: 256 cols x 32 k (4 x 16B per thread)
        #pragma unroll
        for (int i = 0; i < 4; i++) {
            int col = arow + i * 64;
            const uint4 v = *(const uint4*)(Bpk + (size_t)col * 576 + k0 + achk * 8);
            *(uint4*)(Bs + col * 40 + achk * 8) = v;
        }
        __syncthreads();

        bf16x8 af[4], bfr[4];
        #pragma unroll
        for (int mt = 0; mt < 4; mt++)
            af[mt] = *(const bf16x8*)(As + (mt * 16 + l15) * 40 + lh * 8);
        #pragma unroll
        for (int nt = 0; nt < 4; nt++)
            bfr[nt] = *(const bf16x8*)(Bs + (wave * 64 + nt * 16 + l15) * 40 + lh * 8);

        #pragma unroll
        for (int mt = 0; mt < 4; mt++)
            #pragma unroll
            for (int nt = 0; nt < 4; nt++)
                acc[mt][nt] = __builtin_amdgcn_mfma_f32_16x16x32_bf16(af[mt], bfr[nt], acc[mt][nt], 0, 0, 0);

        __syncthreads();
    }

    // epilogue: C/D layout col=lane&15, row=(lane>>4)*4+reg
    #pragma unroll
    for (int nt = 0; nt < 4; nt++) {
        int n = wave * 64 + nt * 16 + l15;
        float bv = bias[n];
        #pragma unroll
        for (int mt = 0; mt < 4; mt++) {
            #pragma unroll
            for (int r = 0; r < 4; r++) {
                int m = m0 + mt * 16 + lh * 4 + r;
                float v = 0.5f * (acc[mt][nt][r] + bv);
                out[(size_t)m * 256 + n] = fmaxf(v, 0.f);
            }
        }
    }
}

// -------------------- launch --------------------
extern "C" void kernel_launch(void* const* d_in, const int* in_sizes, int n_in,
                              void* d_out, int out_size, void* d_ws, size_t ws_size,
                              hipStream_t stream) {
    const float* x_lic = (const float*)d_in[0];
    const float* x_emp = (const float*)d_in[1];
    const float* x_con = (const float*)d_in[2];
    const float* Wl_p  = (const float*)d_in[3];
    const float* Wr_p  = (const float*)d_in[4];
    const float* b_p   = (const float*)d_in[5];
    const float* Wl_q  = (const float*)d_in[6];
    const float* Wr_q  = (const float*)d_in[7];
    const float* b_q   = (const float*)d_in[8];
    const int* ei_p_src = (const int*)d_in[9];
    const int* ei_p_dst = (const int*)d_in[10];
    const int* ei_q_src = (const int*)d_in[11];
    const int* ei_q_dst = (const int*)d_in[12];

    float* ws = (float*)d_ws;
    ushort* aggp = (ushort*)(ws + OFF_AGGP);
    ushort* aggq = (ushort*)(ws + OFF_AGGQ);
    ushort* xl   = (ushort*)(ws + OFF_XL);
    ushort* Bpk  = (ushort*)(ws + OFF_BPK);
    float* bias  = ws + OFF_BIAS;
    int* cnt  = (int*)(ws + OFF_CNT);
    int* curs = (int*)(ws + OFF_CURS);
    int* offp = (int*)(ws + OFF_OFFP);
    int* offq = (int*)(ws + OFF_OFFQ);
    int* curp = (int*)(ws + OFF_CURP);
    int* curq = (int*)(ws + OFF_CURQ);
    int* srtp = (int*)(ws + OFF_SRTP);
    int* srtq = (int*)(ws + OFF_SRTQ);
    float* out = (float*)d_out;

    hipMemsetAsync(cnt, 0, (2 * N_LIC + 128) * sizeof(int), stream);

    prep_kernel<<<(256 * 576 + 256 + 255) / 256, 256, 0, stream>>>(Wl_p, Wl_q, Wr_p, Wr_q, b_p, b_q, Bpk, bias);

    convert_kernel<<<(N_LIC * 256 / 4) / 256, 256, 0, stream>>>(x_lic, xl);

    const int NCHUNK = (E_P + E_Q + 255) / 256;  // 7500 edge chunks
    count_kernel<<<NCHUNK * NR, 256, 0, stream>>>(ei_p_dst, ei_q_dst, cnt);

    assign_kernel<<<(2 * N_LIC + 255) / 256, 256, 0, stream>>>(cnt, offp, offq, curp, curq, curs);

    fill_kernel<<<NCHUNK * NR, 256, 0, stream>>>(ei_p_src, ei_p_dst, ei_q_src, ei_q_dst,
                                                 curp, curq, srtp, srtq);

    aggP_kernel<<<N_LIC / 8, 256, 0, stream>>>(x_emp, offp, cnt, srtp, aggp);
    aggQ_kernel<<<N_LIC / 16, 256, 0, stream>>>(x_con, offq, cnt + N_LIC, srtq, aggq);

    gemm_kernel<<<N_LIC / 64, 256, 0, stream>>>(aggp, aggq, xl, Bpk, bias, out);
}

// Round 4
// 478.644 us; speedup vs baseline: 1.4480x; 1.1038x over previous
//
#include <hip/hip_runtime.h>

// Problem constants
#define N_LIC 40000
#define N_EMP 80000
#define N_CON 60000
#define D_EMP 128
#define D_CON 192
#define HDIM  256
#define E_P   1280000
#define E_Q   640000

#define NR 8                 // dst ranges == XCD count
#define RNG (N_LIC / NR)     // 5000 dst nodes per range

// -------------------- workspace layout (4-byte units) --------------------
// Total 15,674,112 dw = 62.7 MB  (< 64 MiB; R3's 98.5 MB likely overflowed ws)
#define OFF_AGGP   0                                   // 40000x128 bf16 -> 2,560,000 dw
#define OFF_XE     (OFF_AGGP + 2560000)                // 80000x128 bf16 -> 5,120,000 dw
#define OFF_AGGQ   OFF_XE                              // ALIAS: aggq (3.84M dw) reuses xe
                                                       // (xe dead after aggP; aggQ runs after)
#define OFF_XC     (OFF_XE + 5120000)                  // 60000x192 bf16 -> 5,760,000 dw
#define OFF_BPK    (OFF_XC + 5760000)                  // 256x576 bf16 -> 73,728 dw
#define OFF_BIAS   (OFF_BPK + 73728)                   // 256 f
#define OFF_CNT    (OFF_BIAS + 256)                    // 80000 i (P then Q)
#define OFF_CURS   (OFF_CNT + 2 * N_LIC)               // 128 i (2 cursors, line-padded)
#define OFF_OFFP   (OFF_CURS + 128)                    // 40000 i
#define OFF_OFFQ   (OFF_OFFP + N_LIC)                  // 40000 i
#define OFF_CURP   (OFF_OFFQ + N_LIC)                  // 40000 i
#define OFF_CURQ   (OFF_CURP + N_LIC)                  // 40000 i
#define OFF_SRTP   (OFF_CURQ + N_LIC)                  // 1,280,000 i
#define OFF_SRTQ   (OFF_SRTP + E_P)                    // 640,000 i

typedef short bf16x8 __attribute__((ext_vector_type(8)));
typedef float f32x4 __attribute__((ext_vector_type(4)));

__device__ __forceinline__ ushort f2bf(float f) {
    union { float f; uint u; } v; v.f = f;
    return (ushort)((v.u + 0x7fffu + ((v.u >> 16) & 1u)) >> 16);
}

// accumulate a packed pair of bf16 (in one uint) into two fp32 accumulators
__device__ __forceinline__ void acc2(uint u, float& lo, float& hi) {
    union { uint u; float f; } a, b;
    a.u = u << 16;
    b.u = u & 0xffff0000u;
    lo += a.f; hi += b.f;
}

__device__ __forceinline__ uint packbf(float lo, float hi) {
    return (uint)f2bf(lo) | ((uint)f2bf(hi) << 16);
}

// -------------------- prep: pack B = [Wl_p; Wl_q; Wr_p+Wr_q] transposed to [n][k] bf16 ----
__global__ void prep_kernel(const float* __restrict__ Wlp, const float* __restrict__ Wlq,
                            const float* __restrict__ Wrp, const float* __restrict__ Wrq,
                            const float* __restrict__ bp, const float* __restrict__ bq,
                            ushort* __restrict__ Bpk, float* __restrict__ bias) {
    int tid = blockIdx.x * 256 + threadIdx.x;
    if (tid < 256 * 576) {
        int n = tid / 576, k = tid - n * 576;
        float v;
        if (k < 128)      v = Wlp[k * 256 + n];
        else if (k < 320) v = Wlq[(k - 128) * 256 + n];
        else              v = Wrp[(k - 320) * 256 + n] + Wrq[(k - 320) * 256 + n];
        Bpk[tid] = f2bf(v);
    } else if (tid < 256 * 576 + 256) {
        int j = tid - 256 * 576;
        bias[j] = bp[j] + bq[j];
    }
}

// -------------------- fused fp32->bf16 conversion of x_emp, x_con --------------------
#define C_XE (N_EMP * 128 / 4)   // 2,560,000 float4s
#define C_XC (N_CON * 192 / 4)   // 2,880,000
__global__ void convert2_kernel(const float* __restrict__ xemp, const float* __restrict__ xcon,
                                ushort* __restrict__ xe, ushort* __restrict__ xc) {
    int tid = blockIdx.x * 256 + threadIdx.x;
    const float* src; ushort* dst; int i;
    if (tid < C_XE) { src = xemp; dst = xe; i = tid; }
    else            { src = xcon; dst = xc; i = tid - C_XE; }
    float4 v = ((const float4*)src)[i];
    uint2 o;
    o.x = packbf(v.x, v.y);
    o.y = packbf(v.z, v.w);
    ((uint2*)dst)[i] = o;
}

// -------------------- histogram, dst-range partitioned with XCD affinity --------------------
__global__ void count_kernel(const int* __restrict__ dp, const int* __restrict__ dq,
                             int* __restrict__ cnt) {
    int r = blockIdx.x & (NR - 1);
    int chunk = blockIdx.x >> 3;
    int lo = r * RNG, hi = lo + RNG;
    int tid = chunk * 256 + threadIdx.x;
    if (tid < E_P) {
        int d = dp[tid];
        if (d >= lo && d < hi) atomicAdd(&cnt[d], 1);
    } else if (tid < E_P + E_Q) {
        int d = dq[tid - E_P];
        if (d >= lo && d < hi) atomicAdd(&cnt[N_LIC + d], 1);
    }
}

// -------------------- bucket-start assignment via atomic bump allocator --------------------
__global__ __launch_bounds__(256) void assign_kernel(const int* __restrict__ cnt,
                                                     int* __restrict__ offp, int* __restrict__ offq,
                                                     int* __restrict__ curp, int* __restrict__ curq,
                                                     int* __restrict__ cursors) {
    int tid = blockIdx.x * 256 + threadIdx.x;
    int lane = threadIdx.x & 63;
    bool valid = tid < 2 * N_LIC;
    int c = valid ? cnt[tid] : 0;
    int inc = c;
    #pragma unroll
    for (int off = 1; off < 64; off <<= 1) {
        int v = __shfl_up(inc, off, 64);
        if (lane >= off) inc += v;
    }
    int excl = inc - c;
    int wtot = __shfl(inc, 63, 64);
    int rel = (tid >= N_LIC) ? 1 : 0;   // wave-uniform: N_LIC % 64 == 0
    int base = 0;
    if (lane == 0 && wtot > 0) base = atomicAdd(&cursors[rel * 32], wtot);
    base = __shfl(base, 0, 64);
    if (valid) {
        int start = base + excl;
        if (rel == 0) { offp[tid] = start; curp[tid] = start; }
        else          { offq[tid - N_LIC] = start; curq[tid - N_LIC] = start; }
    }
}

// -------------------- bucket-fill, dst-range partitioned with XCD affinity --------------------
__global__ void fill_kernel(const int* __restrict__ sp, const int* __restrict__ dp,
                            const int* __restrict__ sq, const int* __restrict__ dq,
                            int* __restrict__ curp, int* __restrict__ curq,
                            int* __restrict__ srtp, int* __restrict__ srtq) {
    int r = blockIdx.x & (NR - 1);
    int chunk = blockIdx.x >> 3;
    int lo = r * RNG, hi = lo + RNG;
    int tid = chunk * 256 + threadIdx.x;
    if (tid < E_P) {
        int d = dp[tid];
        if (d >= lo && d < hi) {
            int pos = atomicAdd(&curp[d], 1);
            srtp[pos] = sp[tid];
        }
    } else if (tid < E_P + E_Q) {
        int e = tid - E_P;
        int d = dq[e];
        if (d >= lo && d < hi) {
            int pos = atomicAdd(&curq[d], 1);
            srtq[pos] = sq[e];
        }
    }
}

// -------------------- aggregate P: 16 lanes/node, D=128 bf16 in -> bf16 out ------------
// bf16 gather halves the L2-miss traffic vs fp32 (256B/row vs 512B); fp32 accumulate.
__global__ __launch_bounds__(256) void aggP_kernel(const ushort* __restrict__ xe,
                                                   const int* __restrict__ offs,
                                                   const int* __restrict__ cnt,
                                                   const int* __restrict__ sorted,
                                                   ushort* __restrict__ agg) {
    int g = blockIdx.x * 16 + (threadIdx.x >> 4);
    int c = threadIdx.x & 15;
    int beg = offs[g], deg = cnt[g], end = beg + deg;
    float a0=0,a1=0,a2=0,a3=0,a4=0,a5=0,a6=0,a7=0;
    for (int eb = beg; eb < end; eb += 16) {
        int n = end - eb; if (n > 16) n = 16;
        int my = (c < n) ? sorted[eb + c] : 0;
        for (int j = 0; j < n; j++) {
            int s = __shfl(my, j, 16);
            uint4 v = *(const uint4*)(xe + (size_t)s * D_EMP + c * 8);
            acc2(v.x, a0, a1); acc2(v.y, a2, a3);
            acc2(v.z, a4, a5); acc2(v.w, a6, a7);
        }
    }
    float inv = 1.0f / fmaxf((float)deg, 1.0f);
    uint4 o;
    o.x = packbf(a0 * inv, a1 * inv);
    o.y = packbf(a2 * inv, a3 * inv);
    o.z = packbf(a4 * inv, a5 * inv);
    o.w = packbf(a6 * inv, a7 * inv);
    *(uint4*)(agg + (size_t)g * D_EMP + c * 8) = o;
}

// -------------------- aggregate Q: 16 lanes/node, D=192 bf16 in -> bf16 out ------------
__global__ __launch_bounds__(256) void aggQ_kernel(const ushort* __restrict__ xc,
                                                   const int* __restrict__ offs,
                                                   const int* __restrict__ cnt,
                                                   const int* __restrict__ sorted,
                                                   ushort* __restrict__ agg) {
    int g = blockIdx.x * 16 + (threadIdx.x >> 4);
    int c = threadIdx.x & 15;
    int beg = offs[g], deg = cnt[g], end = beg + deg;
    float a0=0,a1=0,a2=0,a3=0,a4=0,a5=0,a6=0,a7=0,a8=0,a9=0,a10=0,a11=0;
    for (int eb = beg; eb < end; eb += 16) {
        int n = end - eb; if (n > 16) n = 16;
        int my = (c < n) ? sorted[eb + c] : 0;
        for (int j = 0; j < n; j++) {
            int s = __shfl(my, j, 16);
            const ushort* row = xc + (size_t)s * D_CON + c * 12;
            uint2 v0 = *(const uint2*)(row + 0);
            uint2 v1 = *(const uint2*)(row + 4);
            uint2 v2 = *(const uint2*)(row + 8);
            acc2(v0.x, a0, a1);  acc2(v0.y, a2, a3);
            acc2(v1.x, a4, a5);  acc2(v1.y, a6, a7);
            acc2(v2.x, a8, a9);  acc2(v2.y, a10, a11);
        }
    }
    float inv = 1.0f / fmaxf((float)deg, 1.0f);
    ushort* o = agg + (size_t)g * D_CON + c * 12;
    uint2 w0, w1, w2;
    w0.x = packbf(a0 * inv, a1 * inv);   w0.y = packbf(a2 * inv, a3 * inv);
    w1.x = packbf(a4 * inv, a5 * inv);   w1.y = packbf(a6 * inv, a7 * inv);
    w2.x = packbf(a8 * inv, a9 * inv);   w2.y = packbf(a10 * inv, a11 * inv);
    *(uint2*)(o + 0) = w0;
    *(uint2*)(o + 4) = w1;
    *(uint2*)(o + 8) = w2;
}

// -------------------- MFMA bf16 GEMM + bias + relu --------------------
// C[40000,256] = relu(0.5*([aggp|aggq|bf16(x_lic)] @ B + bias)); B prepacked [n=256][k=576].
// x_lic is read fp32 and converted during A-tile staging (no xl buffer; saves ws + traffic).
// BM=64, BN=256 (full), BK=32, 4 waves, each wave 64 rows x 64 cols = 4x4 mfma tiles.
__global__ __launch_bounds__(256) void gemm_kernel(
    const ushort* __restrict__ aggp, const ushort* __restrict__ aggq,
    const float* __restrict__ xlic, const ushort* __restrict__ Bpk,
    const float* __restrict__ bias, float* __restrict__ out)
{
    __shared__ __align__(16) ushort As[64 * 40];   // [m][k], k padded 32->40
    __shared__ __align__(16) ushort Bs[256 * 40];  // [n][k]

    const int t = threadIdx.x;
    const int m0 = blockIdx.x * 64;
    const int lane = t & 63;
    const int wave = t >> 6;
    const int arow = t >> 2;   // 0..63
    const int achk = t & 3;    // 0..3
    const int l15 = lane & 15;
    const int lh  = lane >> 4; // 0..3

    f32x4 acc[4][4];
    #pragma unroll
    for (int i = 0; i < 4; i++)
        #pragma unroll
        for (int j = 0; j < 4; j++)
            acc[i][j] = (f32x4){0.f, 0.f, 0.f, 0.f};

    for (int k0 = 0; k0 < 576; k0 += 32) {
        // stage A tile: 64 rows x 32 k (16B of bf16 per thread)
        if (k0 < 320) {
            const ushort* Asrc; int ldA; int ko;
            if (k0 < 128) { Asrc = aggp; ldA = 128; ko = k0; }
            else          { Asrc = aggq; ldA = 192; ko = k0 - 128; }
            const uint4 v = *(const uint4*)(Asrc + (size_t)(m0 + arow) * ldA + ko + achk * 8);
            *(uint4*)(As + arow * 40 + achk * 8) = v;
        } else {
            const float* src = xlic + (size_t)(m0 + arow) * 256 + (k0 - 320) + achk * 8;
            float4 v0 = *(const float4*)(src + 0);
            float4 v1 = *(const float4*)(src + 4);
            uint4 o;
            o.x = packbf(v0.x, v0.y);
            o.y = packbf(v0.z, v0.w);
            o.z = packbf(v1.x, v1.y);
            o.w = packbf(v1.z, v1.w);
            *(uint4*)(As + arow * 40 + achk * 8) = o;
        }
        // stage B tile: 256 cols x 32 k (4 x 16B per thread)
        #pragma unroll
        for (int i = 0; i < 4; i++) {
            int col = arow + i * 64;
            const uint4 v = *(const uint4*)(Bpk + (size_t)col * 576 + k0 + achk * 8);
            *(uint4*)(Bs + col * 40 + achk * 8) = v;
        }
        __syncthreads();

        bf16x8 af[4], bfr[4];
        #pragma unroll
        for (int mt = 0; mt < 4; mt++)
            af[mt] = *(const bf16x8*)(As + (mt * 16 + l15) * 40 + lh * 8);
        #pragma unroll
        for (int nt = 0; nt < 4; nt++)
            bfr[nt] = *(const bf16x8*)(Bs + (wave * 64 + nt * 16 + l15) * 40 + lh * 8);

        #pragma unroll
        for (int mt = 0; mt < 4; mt++)
            #pragma unroll
            for (int nt = 0; nt < 4; nt++)
                acc[mt][nt] = __builtin_amdgcn_mfma_f32_16x16x32_bf16(af[mt], bfr[nt], acc[mt][nt], 0, 0, 0);

        __syncthreads();
    }

    // epilogue: C/D layout col=lane&15, row=(lane>>4)*4+reg
    #pragma unroll
    for (int nt = 0; nt < 4; nt++) {
        int n = wave * 64 + nt * 16 + l15;
        float bv = bias[n];
        #pragma unroll
        for (int mt = 0; mt < 4; mt++) {
            #pragma unroll
            for (int r = 0; r < 4; r++) {
                int m = m0 + mt * 16 + lh * 4 + r;
                float v = 0.5f * (acc[mt][nt][r] + bv);
                out[(size_t)m * 256 + n] = fmaxf(v, 0.f);
            }
        }
    }
}

// -------------------- launch --------------------
extern "C" void kernel_launch(void* const* d_in, const int* in_sizes, int n_in,
                              void* d_out, int out_size, void* d_ws, size_t ws_size,
                              hipStream_t stream) {
    const float* x_lic = (const float*)d_in[0];
    const float* x_emp = (const float*)d_in[1];
    const float* x_con = (const float*)d_in[2];
    const float* Wl_p  = (const float*)d_in[3];
    const float* Wr_p  = (const float*)d_in[4];
    const float* b_p   = (const float*)d_in[5];
    const float* Wl_q  = (const float*)d_in[6];
    const float* Wr_q  = (const float*)d_in[7];
    const float* b_q   = (const float*)d_in[8];
    const int* ei_p_src = (const int*)d_in[9];
    const int* ei_p_dst = (const int*)d_in[10];
    const int* ei_q_src = (const int*)d_in[11];
    const int* ei_q_dst = (const int*)d_in[12];

    float* ws = (float*)d_ws;
    ushort* aggp = (ushort*)(ws + OFF_AGGP);
    ushort* aggq = (ushort*)(ws + OFF_AGGQ);   // aliases xe (safe: xe dead after aggP)
    ushort* xe   = (ushort*)(ws + OFF_XE);
    ushort* xc   = (ushort*)(ws + OFF_XC);
    ushort* Bpk  = (ushort*)(ws + OFF_BPK);
    float* bias  = ws + OFF_BIAS;
    int* cnt  = (int*)(ws + OFF_CNT);
    int* curs = (int*)(ws + OFF_CURS);
    int* offp = (int*)(ws + OFF_OFFP);
    int* offq = (int*)(ws + OFF_OFFQ);
    int* curp = (int*)(ws + OFF_CURP);
    int* curq = (int*)(ws + OFF_CURQ);
    int* srtp = (int*)(ws + OFF_SRTP);
    int* srtq = (int*)(ws + OFF_SRTQ);
    float* out = (float*)d_out;

    hipMemsetAsync(cnt, 0, (2 * N_LIC + 128) * sizeof(int), stream);

    prep_kernel<<<(256 * 576 + 256 + 255) / 256, 256, 0, stream>>>(Wl_p, Wl_q, Wr_p, Wr_q, b_p, b_q, Bpk, bias);

    convert2_kernel<<<(C_XE + C_XC) / 256, 256, 0, stream>>>(x_emp, x_con, xe, xc);

    const int NCHUNK = (E_P + E_Q + 255) / 256;  // 7500 edge chunks
    count_kernel<<<NCHUNK * NR, 256, 0, stream>>>(ei_p_dst, ei_q_dst, cnt);

    assign_kernel<<<(2 * N_LIC + 255) / 256, 256, 0, stream>>>(cnt, offp, offq, curp, curq, curs);

    fill_kernel<<<NCHUNK * NR, 256, 0, stream>>>(ei_p_src, ei_p_dst, ei_q_src, ei_q_dst,
                                                 curp, curq, srtp, srtq);

    // aggP first (consumes xe), then aggQ (writes aggq INTO xe's space)
    aggP_kernel<<<N_LIC / 16, 256, 0, stream>>>(xe, offp, cnt, srtp, aggp);
    aggQ_kernel<<<N_LIC / 16, 256, 0, stream>>>(xc, offq, cnt + N_LIC, srtq, aggq);

    gemm_kernel<<<N_LIC / 64, 256, 0, stream>>>(aggp, aggq, x_lic, Bpk, bias, out);
}